// Round 9
// baseline (57.121 us; speedup 1.0000x reference)
//
#include <hip/hip_runtime.h>

// Problem constants (match the JAX reference)
constexpr int BATCH      = 256;
constexpr int T          = 100;
constexpr int J          = 32;
constexpr int EDGES      = 101;
constexpr int NBINS      = 100;
constexpr int ROW_FLOATS = T * J * 3;      // 9600 floats per row
constexpr int TPB        = 20;             // timesteps per block (100 = 5 x 20, exact)
constexpr int BPR        = 5;              // blocks per row
constexpr int NT1        = 640;            // 10 waves = 20 half-waves = 20 timestep owners
constexpr int TSTRIDE    = 97;             // float2 units per timestep (96 used + 1 pad)
constexpr int NREP       = 32;             // histogram replicas (rep = lane&31)
constexpr float EPSF     = 1e-8f;
constexpr float NTOT     = 102400.0f;      // T*J*J = counts.sum()

// ws layout: [0,1KB) per-row max-squared-distance bits; [1KB, 1KB+200KB) counts
constexpr size_t WS_HIST_OFF = 1024;
constexpr size_t WS_BYTES    = WS_HIST_OFF + (size_t)BATCH * 2 * NBINS * sizeof(unsigned);

// Raw v_sqrt_f32 (~1 ulp) — guess only; exact binning via squared-domain thresholds.
__device__ __forceinline__ float sqrt_approx(float s) {
    float r;
    asm("v_sqrt_f32 %0, %1" : "=v"(r) : "v"(s));
    return r;
}

// Stage 20 timesteps of both datasets, interleaved float2 units:
// point (t,c) at t*TSTRIDE + c*3 = {x1y1, x2y2, z1z2}. 640 threads = 640 points.
__device__ __forceinline__ void stage_seg(float2* spt, const float* p1, const float* p2, int tid) {
    const int t = tid >> 5, c = tid & 31;
    const int base = t * TSTRIDE + c * 3;
    spt[base + 0] = make_float2(p1[3 * tid],     p1[3 * tid + 1]);
    spt[base + 1] = make_float2(p2[3 * tid],     p2[3 * tid + 1]);
    spt[base + 2] = make_float2(p1[3 * tid + 2], p2[3 * tid + 2]);
}

// ---- K1: per-row max squared distance (sqrt monotone => sqrt(max) later).
__global__ __launch_bounds__(NT1)
void k_max(const float* __restrict__ g1all, const float* __restrict__ g2all,
           unsigned int* __restrict__ wmax)
{
#pragma clang fp contract(off)
    __shared__ float2 spt[TPB * TSTRIDE];
    __shared__ float sred[NT1 / 64];
    const int tid = threadIdx.x, bid = blockIdx.x;
    const int row = bid / BPR, tseg = bid - row * BPR;
    const float* p1 = g1all + (size_t)row * ROW_FLOATS + tseg * (TPB * J * 3);
    const float* p2 = g2all + (size_t)row * ROW_FLOATS + tseg * (TPB * J * 3);

    stage_seg(spt, p1, p2, tid);
    __syncthreads();

    // Rotation enumeration: half-wave owns one timestep; lane a vs (a+k)&31, k=1..16.
    const int hw = tid >> 5, a = tid & 31;
    const int b = hw * TSTRIDE;
    const float2 o0 = spt[b + a * 3];
    const float2 o1 = spt[b + a * 3 + 1];
    const float2 o2 = spt[b + a * 3 + 2];
    float vmax = 0.0f;
#pragma unroll 8
    for (int k = 1; k <= 16; ++k) {
        const int c = b + ((a + k) & 31) * 3;
        const float2 c0 = spt[c], c1 = spt[c + 1], c2 = spt[c + 2];
        float dx1 = o0.x - c0.x, dy1 = o0.y - c0.y, dz1 = o2.x - c2.x;
        float s1 = dx1 * dx1 + dy1 * dy1 + dz1 * dz1;   // ((x^2+y^2)+z^2), no FMA
        float dx2 = o1.x - c1.x, dy2 = o1.y - c1.y, dz2 = o2.y - c2.y;
        float s2 = dx2 * dx2 + dy2 * dy2 + dz2 * dz2;
        vmax = fmaxf(vmax, fmaxf(s1, s2));
    }
    for (int off = 32; off > 0; off >>= 1)
        vmax = fmaxf(vmax, __shfl_down(vmax, off, 64));
    if ((tid & 63) == 0) sred[tid >> 6] = vmax;
    __syncthreads();
    if (tid == 0) {
        float m = sred[0];
        for (int w = 1; w < NT1 / 64; ++w) m = fmaxf(m, sred[w]);
        // Non-negative floats: bit pattern order == value order.
        atomicMax(&wmax[row], __float_as_uint(m));
    }
}

// ---- K2: histogram both datasets into global counts (exact binning).
__global__ __launch_bounds__(NT1)
void k_hist(const float* __restrict__ g1all, const float* __restrict__ g2all,
            const unsigned int* __restrict__ wmax, unsigned int* __restrict__ whist)
{
#pragma clang fp contract(off)
    __shared__ float2 spt[TPB * TSTRIDE];            // 15,520 B
    __shared__ unsigned int hist[2][NREP][EDGES];    // 25,856 B
    __shared__ float sqe[EDGES];                     // squared-domain thresholds m_i
    __shared__ float2 SQ2[NBINS];                    // {m_i, m_{i+1}} pairs
    const int tid = threadIdx.x, bid = blockIdx.x;
    const int row = bid / BPR, tseg = bid - row * BPR;
    const float* p1 = g1all + (size_t)row * ROW_FLOATS + tseg * (TPB * J * 3);
    const float* p2 = g2all + (size_t)row * ROW_FLOATS + tseg * (TPB * J * 3);

    stage_seg(spt, p1, p2, tid);
    for (int k = tid; k < 2 * NREP * EDGES; k += NT1)
        (&hist[0][0][0])[k] = 0u;

    // mx = RN-sqrt of the row's max squared distance (same value as one-kernel
    // versions, which validated absmax 0.0). mn == 0 exactly (diagonal pairs).
    const float mx   = __fsqrt_rn(__uint_as_float(wmax[row]));
    const float invw = 100.0f / mx;                  // guess only — probes are exact

    // Squared-domain thresholds: m_i = smallest float y>=0 with RN(sqrt(y)) >= e[i],
    // e[i] = mx * ((float)i * 0.01f), e[100] = mx (endpoint pinned). Then
    // RN(sqrt(s)) >= e[i]  <=>  s >= m_i: binning s EXACTLY reproduces the reference.
    if (tid < EDGES) {
        float e = (tid == EDGES - 1) ? mx : __fmul_rn(mx, __fmul_rn((float)tid, 0.01f));
        float y = 0.0f;                              // e[0] == 0 -> m_0 = 0
        if (tid > 0) {
            y = __fmul_rn(e, e);
            for (int it = 0; it < 4 && __fsqrt_rn(y) < e; ++it)
                y = __int_as_float(__float_as_int(y) + 1);   // safety (shouldn't fire)
            for (int it = 0; it < 8; ++it) {
                float py = __int_as_float(__float_as_int(y) - 1);
                if (__fsqrt_rn(py) >= e) y = py; else break;
            }
        }
        sqe[tid] = y;
    }
    __syncthreads();
    if (tid < NBINS) SQ2[tid] = make_float2(sqe[tid], sqe[tid + 1]);
    __syncthreads();

    // Pass B: rotation enumeration; k<16 weight 2 (unordered pair), k==16 weight 1
    // (each side counts it once; (x-y)^2 == (y-x)^2 bitwise so exact).
    const int hw = tid >> 5, a = tid & 31;
    const int b = hw * TSTRIDE;
    const float2 o0 = spt[b + a * 3];
    const float2 o1 = spt[b + a * 3 + 1];
    const float2 o2 = spt[b + a * 3 + 2];
    unsigned int* __restrict__ h1 = &hist[0][a][0];
    unsigned int* __restrict__ h2 = &hist[1][a][0];
#pragma unroll 8
    for (int k = 1; k <= 16; ++k) {
        const int c = b + ((a + k) & 31) * 3;
        const float2 c0 = spt[c], c1 = spt[c + 1], c2 = spt[c + 2];
        float dx1 = o0.x - c0.x, dy1 = o0.y - c0.y, dz1 = o2.x - c2.x;
        float s1 = dx1 * dx1 + dy1 * dy1 + dz1 * dz1;
        float dx2 = o1.x - c1.x, dy2 = o1.y - c1.y, dz2 = o2.y - c2.y;
        float s2 = dx2 * dx2 + dy2 * dy2 + dz2 * dz2;

        int i1 = (int)(sqrt_approx(s1) * invw);      // guess within +-1 (proven)
        int i2 = (int)(sqrt_approx(s2) * invw);
        i1 = i1 < 0 ? 0 : (i1 > 99 ? 99 : i1);
        i2 = i2 < 0 ? 0 : (i2 > 99 ? 99 : i2);
        float2 t1 = SQ2[i1];
        float2 t2 = SQ2[i2];
        i1 += (s1 >= t1.y) ? 1 : 0;                  // exclusive with the decrement
        i1 -= (s1 <  t1.x) ? 1 : 0;
        i2 += (s2 >= t2.y) ? 1 : 0;
        i2 -= (s2 <  t2.x) ? 1 : 0;
        i1 = i1 > 99 ? 99 : i1;                      // == reference clip to NBINS-1
        i2 = i2 > 99 ? 99 : i2;

        const unsigned int wgt = (k < 16) ? 2u : 1u;
        atomicAdd(&h1[i1], wgt);
        atomicAdd(&h2[i2], wgt);
    }
    __syncthreads();

    // Merge LDS replicas into global counts (device-scope atomics).
    if (tid < 2 * NBINS) {
        const int ds = tid / NBINS, bn = tid - ds * NBINS;
        unsigned int s = 0;
        for (int rr = 0; rr < NREP; ++rr) s += hist[ds][rr][bn];
        atomicAdd(&whist[(row * 2 + ds) * NBINS + bn], s);
    }
}

// ---- K3: per-row JSD epilogue (identical arithmetic to the absmax-0.0 version).
__global__ __launch_bounds__(128)
void k_jsd(const unsigned int* __restrict__ wmax, const unsigned int* __restrict__ whist,
           float* __restrict__ out)
{
#pragma clang fp contract(off)
    __shared__ float edg[EDGES];
    __shared__ float sterm[NBINS];
    const int tid = threadIdx.x, row = blockIdx.x;
    const float mx = __fsqrt_rn(__uint_as_float(wmax[row]));
    if (tid < EDGES) {
        float w1 = (tid == EDGES - 1) ? 1.0f : ((float)tid * 0.01f);
        edg[tid] = mx * w1;
    }
    __syncthreads();
    if (tid < NBINS) {
        unsigned int c1 = whist[(row * 2 + 0) * NBINS + tid];
        unsigned int c2 = whist[(row * 2 + 1) * NBINS + tid];
        if (tid == 0) { c1 += T * J; c2 += T * J; }  // diagonal zeros -> bin 0

        float w   = edg[tid + 1] - edg[tid];         // jnp.diff(edges)
        float den = __fmul_rn(NTOT, w);
        float px  = __fdiv_rn((float)c1, den);
        float qx  = __fdiv_rn((float)c2, den);
        float m   = (px + qx) * 0.5f;
        float lm  = logf(m + EPSF);
        sterm[tid] = px * (logf(px + EPSF) - lm) + qx * (logf(qx + EPSF) - lm);
    }
    __syncthreads();
    if (tid == 0) {
        float acc = 0.0f;
        for (int i = 0; i < NBINS; ++i) acc += sterm[i];
        out[row] = acc * 0.5f;
    }
}

extern "C" void kernel_launch(void* const* d_in, const int* in_sizes, int n_in,
                              void* d_out, int out_size, void* d_ws, size_t ws_size,
                              hipStream_t stream) {
    const float* d1 = (const float*)d_in[0];
    const float* d2 = (const float*)d_in[1];
    float* out = (float*)d_out;
    unsigned int* wmax  = (unsigned int*)d_ws;
    unsigned int* whist = (unsigned int*)((char*)d_ws + WS_HIST_OFF);

    hipMemsetAsync(d_ws, 0, WS_BYTES, stream);   // graph-capturable; deterministic
    k_max <<<BATCH * BPR, NT1, 0, stream>>>(d1, d2, wmax);
    k_hist<<<BATCH * BPR, NT1, 0, stream>>>(d1, d2, wmax, whist);
    k_jsd <<<BATCH, 128, 0, stream>>>(wmax, whist, out);
}

// Round 10
// 52.464 us; speedup vs baseline: 1.0888x; 1.0888x over previous
//
#include <hip/hip_runtime.h>

// Problem constants (match the JAX reference)
constexpr int BATCH      = 256;
constexpr int T          = 100;
constexpr int J          = 32;
constexpr int EDGES      = 101;
constexpr int NBINS      = 100;
constexpr int ROW_FLOATS = T * J * 3;      // 9600 floats per row
constexpr int TPB        = 20;             // timesteps per block (100 = 5 x 20, exact)
constexpr int BPR        = 5;              // blocks per row
constexpr int NT1        = 640;            // 10 waves = 20 half-waves = 20 timestep owners
constexpr int TSTRIDE    = 97;             // float2 units per timestep (96 used + 1 pad)
constexpr int NREP       = 32;             // histogram replicas (rep = lane&31)
constexpr float EPSF     = 1e-8f;
constexpr float NTOT     = 102400.0f;      // T*J*J = counts.sum()

// ws layout (ALL bytes written by kernels before any read — no memset needed):
//   [0, 5120)            float  wmax[BATCH*BPR]   per-BLOCK max squared distance
//   [5120, 5120+200KB)   uint   whist[BATCH][2][NBINS]  (zeroed by K1, atomics in K2)
constexpr size_t WS_HIST_OFF = 5120;

// Raw v_sqrt_f32 (~1 ulp) — guess only; exact binning via squared-domain thresholds.
__device__ __forceinline__ float sqrt_approx(float s) {
    float r;
    asm("v_sqrt_f32 %0, %1" : "=v"(r) : "v"(s));
    return r;
}

// Stage 20 timesteps of both datasets, interleaved float2 units:
// point (t,c) at t*TSTRIDE + c*3 = {x1y1, x2y2, z1z2}. 640 threads = 640 points.
__device__ __forceinline__ void stage_seg(float2* spt, const float* p1, const float* p2, int tid) {
    const int t = tid >> 5, c = tid & 31;
    const int base = t * TSTRIDE + c * 3;
    spt[base + 0] = make_float2(p1[3 * tid],     p1[3 * tid + 1]);
    spt[base + 1] = make_float2(p2[3 * tid],     p2[3 * tid + 1]);
    spt[base + 2] = make_float2(p1[3 * tid + 2], p2[3 * tid + 2]);
}

// Row max squared distance from the 5 per-block partials (plain f32 max — exact).
__device__ __forceinline__ float row_mx(const float* __restrict__ wmax, int row) {
    float m = wmax[row * BPR];
    for (int i = 1; i < BPR; ++i) m = fmaxf(m, wmax[row * BPR + i]);
    return __fsqrt_rn(m);
}

// ---- K1: per-block max squared distance + zero this row's global hist slice.
__global__ __launch_bounds__(NT1)
void k_max(const float* __restrict__ g1all, const float* __restrict__ g2all,
           float* __restrict__ wmax, unsigned int* __restrict__ whist)
{
#pragma clang fp contract(off)
    __shared__ float2 spt[TPB * TSTRIDE];
    __shared__ float sred[NT1 / 64];
    const int tid = threadIdx.x, bid = blockIdx.x;
    const int row = bid / BPR, tseg = bid - row * BPR;
    const float* p1 = g1all + (size_t)row * ROW_FLOATS + tseg * (TPB * J * 3);
    const float* p2 = g2all + (size_t)row * ROW_FLOATS + tseg * (TPB * J * 3);

    // Zero this row's 200 hist words (all 5 sibling blocks write 0 — benign;
    // K1 -> K2 launch ordering makes it visible before K2's atomics).
    if (tid < 2 * NBINS) whist[row * 2 * NBINS + tid] = 0u;

    stage_seg(spt, p1, p2, tid);
    __syncthreads();

    // Rotation enumeration: half-wave owns one timestep; lane a vs (a+k)&31, k=1..16.
    const int hw = tid >> 5, a = tid & 31;
    const int b = hw * TSTRIDE;
    const float2 o0 = spt[b + a * 3];
    const float2 o1 = spt[b + a * 3 + 1];
    const float2 o2 = spt[b + a * 3 + 2];
    float vmax = 0.0f;
#pragma unroll 8
    for (int k = 1; k <= 16; ++k) {
        const int c = b + ((a + k) & 31) * 3;
        const float2 c0 = spt[c], c1 = spt[c + 1], c2 = spt[c + 2];
        float dx1 = o0.x - c0.x, dy1 = o0.y - c0.y, dz1 = o2.x - c2.x;
        float s1 = dx1 * dx1 + dy1 * dy1 + dz1 * dz1;   // ((x^2+y^2)+z^2), no FMA
        float dx2 = o1.x - c1.x, dy2 = o1.y - c1.y, dz2 = o2.y - c2.y;
        float s2 = dx2 * dx2 + dy2 * dy2 + dz2 * dz2;
        vmax = fmaxf(vmax, fmaxf(s1, s2));
    }
    for (int off = 32; off > 0; off >>= 1)
        vmax = fmaxf(vmax, __shfl_down(vmax, off, 64));
    if ((tid & 63) == 0) sred[tid >> 6] = vmax;
    __syncthreads();
    if (tid == 0) {
        float m = sred[0];
        for (int w = 1; w < NT1 / 64; ++w) m = fmaxf(m, sred[w]);
        wmax[bid] = m;                               // plain store — no init needed
    }
}

// ---- K2: histogram both datasets into global counts (exact binning).
__global__ __launch_bounds__(NT1)
void k_hist(const float* __restrict__ g1all, const float* __restrict__ g2all,
            const float* __restrict__ wmax, unsigned int* __restrict__ whist)
{
#pragma clang fp contract(off)
    __shared__ float2 spt[TPB * TSTRIDE];            // 15,520 B
    __shared__ unsigned int hist[2][NREP][EDGES];    // 25,856 B
    __shared__ float sqe[EDGES];                     // squared-domain thresholds m_i
    __shared__ float2 SQ2[NBINS];                    // {m_i, m_{i+1}} pairs
    const int tid = threadIdx.x, bid = blockIdx.x;
    const int row = bid / BPR, tseg = bid - row * BPR;
    const float* p1 = g1all + (size_t)row * ROW_FLOATS + tseg * (TPB * J * 3);
    const float* p2 = g2all + (size_t)row * ROW_FLOATS + tseg * (TPB * J * 3);

    stage_seg(spt, p1, p2, tid);
    for (int k = tid; k < 2 * NREP * EDGES; k += NT1)
        (&hist[0][0][0])[k] = 0u;

    // mx = RN-sqrt of the row's max squared distance (bitwise == one-kernel
    // versions, which validated absmax 0.0). mn == 0 exactly (diagonal pairs).
    const float mx   = row_mx(wmax, row);
    const float invw = 100.0f / mx;                  // guess only — probes are exact

    // Squared-domain thresholds: m_i = smallest float y>=0 with RN(sqrt(y)) >= e[i],
    // e[i] = mx * ((float)i * 0.01f), e[100] = mx (endpoint pinned). Then
    // RN(sqrt(s)) >= e[i]  <=>  s >= m_i: binning s EXACTLY reproduces the reference.
    if (tid < EDGES) {
        float e = (tid == EDGES - 1) ? mx : __fmul_rn(mx, __fmul_rn((float)tid, 0.01f));
        float y = 0.0f;                              // e[0] == 0 -> m_0 = 0
        if (tid > 0) {
            y = __fmul_rn(e, e);
            for (int it = 0; it < 4 && __fsqrt_rn(y) < e; ++it)
                y = __int_as_float(__float_as_int(y) + 1);   // safety (shouldn't fire)
            for (int it = 0; it < 8; ++it) {
                float py = __int_as_float(__float_as_int(y) - 1);
                if (__fsqrt_rn(py) >= e) y = py; else break;
            }
        }
        sqe[tid] = y;
    }
    __syncthreads();
    if (tid < NBINS) SQ2[tid] = make_float2(sqe[tid], sqe[tid + 1]);
    __syncthreads();

    // Pass B: rotation enumeration; k<16 weight 2 (unordered pair), k==16 weight 1
    // (each side counts it once; (x-y)^2 == (y-x)^2 bitwise so exact).
    const int hw = tid >> 5, a = tid & 31;
    const int b = hw * TSTRIDE;
    const float2 o0 = spt[b + a * 3];
    const float2 o1 = spt[b + a * 3 + 1];
    const float2 o2 = spt[b + a * 3 + 2];
    unsigned int* __restrict__ h1 = &hist[0][a][0];
    unsigned int* __restrict__ h2 = &hist[1][a][0];
#pragma unroll 8
    for (int k = 1; k <= 16; ++k) {
        const int c = b + ((a + k) & 31) * 3;
        const float2 c0 = spt[c], c1 = spt[c + 1], c2 = spt[c + 2];
        float dx1 = o0.x - c0.x, dy1 = o0.y - c0.y, dz1 = o2.x - c2.x;
        float s1 = dx1 * dx1 + dy1 * dy1 + dz1 * dz1;
        float dx2 = o1.x - c1.x, dy2 = o1.y - c1.y, dz2 = o2.y - c2.y;
        float s2 = dx2 * dx2 + dy2 * dy2 + dz2 * dz2;

        int i1 = (int)(sqrt_approx(s1) * invw);      // guess within +-1 (proven)
        int i2 = (int)(sqrt_approx(s2) * invw);
        i1 = i1 < 0 ? 0 : (i1 > 99 ? 99 : i1);
        i2 = i2 < 0 ? 0 : (i2 > 99 ? 99 : i2);
        float2 t1 = SQ2[i1];
        float2 t2 = SQ2[i2];
        i1 += (s1 >= t1.y) ? 1 : 0;                  // exclusive with the decrement
        i1 -= (s1 <  t1.x) ? 1 : 0;
        i2 += (s2 >= t2.y) ? 1 : 0;
        i2 -= (s2 <  t2.x) ? 1 : 0;
        i1 = i1 > 99 ? 99 : i1;                      // == reference clip to NBINS-1
        i2 = i2 > 99 ? 99 : i2;

        const unsigned int wgt = (k < 16) ? 2u : 1u;
        atomicAdd(&h1[i1], wgt);
        atomicAdd(&h2[i2], wgt);
    }
    __syncthreads();

    // Merge LDS replicas into global counts (device-scope atomics).
    if (tid < 2 * NBINS) {
        const int ds = tid / NBINS, bn = tid - ds * NBINS;
        unsigned int s = 0;
        for (int rr = 0; rr < NREP; ++rr) s += hist[ds][rr][bn];
        atomicAdd(&whist[(row * 2 + ds) * NBINS + bn], s);
    }
}

// ---- K3: per-row JSD epilogue (identical arithmetic to the absmax-0.0 version).
__global__ __launch_bounds__(128)
void k_jsd(const float* __restrict__ wmax, const unsigned int* __restrict__ whist,
           float* __restrict__ out)
{
#pragma clang fp contract(off)
    __shared__ float edg[EDGES];
    __shared__ float sterm[NBINS];
    const int tid = threadIdx.x, row = blockIdx.x;
    const float mx = row_mx(wmax, row);
    if (tid < EDGES) {
        float w1 = (tid == EDGES - 1) ? 1.0f : ((float)tid * 0.01f);
        edg[tid] = mx * w1;
    }
    __syncthreads();
    if (tid < NBINS) {
        unsigned int c1 = whist[(row * 2 + 0) * NBINS + tid];
        unsigned int c2 = whist[(row * 2 + 1) * NBINS + tid];
        if (tid == 0) { c1 += T * J; c2 += T * J; }  // diagonal zeros -> bin 0

        float w   = edg[tid + 1] - edg[tid];         // jnp.diff(edges)
        float den = __fmul_rn(NTOT, w);
        float px  = __fdiv_rn((float)c1, den);
        float qx  = __fdiv_rn((float)c2, den);
        float m   = (px + qx) * 0.5f;
        float lm  = logf(m + EPSF);
        sterm[tid] = px * (logf(px + EPSF) - lm) + qx * (logf(qx + EPSF) - lm);
    }
    __syncthreads();
    if (tid == 0) {
        float acc = 0.0f;
        for (int i = 0; i < NBINS; ++i) acc += sterm[i];
        out[row] = acc * 0.5f;
    }
}

extern "C" void kernel_launch(void* const* d_in, const int* in_sizes, int n_in,
                              void* d_out, int out_size, void* d_ws, size_t ws_size,
                              hipStream_t stream) {
    const float* d1 = (const float*)d_in[0];
    const float* d2 = (const float*)d_in[1];
    float* out = (float*)d_out;
    float*        wmax  = (float*)d_ws;
    unsigned int* whist = (unsigned int*)((char*)d_ws + WS_HIST_OFF);

    k_max <<<BATCH * BPR, NT1, 0, stream>>>(d1, d2, wmax, whist);
    k_hist<<<BATCH * BPR, NT1, 0, stream>>>(d1, d2, wmax, whist);
    k_jsd <<<BATCH, 128, 0, stream>>>(wmax, whist, out);
}